// Round 5
// baseline (418.649 us; speedup 1.0000x reference)
//
#include <hip/hip_runtime.h>

typedef __bf16 bf16_t;
typedef __bf16 bf16x4 __attribute__((ext_vector_type(4)));
typedef __bf16 bf16x8 __attribute__((ext_vector_type(8)));
typedef float f32x4 __attribute__((ext_vector_type(4)));

#define MFMA16(a, b, c) __builtin_amdgcn_mfma_f32_16x16x32_bf16((a), (b), (c), 0, 0, 0)

#define FENCE asm volatile("" ::: "memory")
#define BAR()                        \
  do {                               \
    FENCE;                           \
    __builtin_amdgcn_s_barrier();    \
    FENCE;                           \
  } while (0)
#define WAITLGKM(n) asm volatile("s_waitcnt lgkmcnt(" #n ")" ::: "memory")

// async global->LDS, 16B per lane. LDS dest must be wave-uniform base + lane*16.
__device__ __forceinline__ void gl_lds16(const bf16_t* g, bf16_t* l) {
  __builtin_amdgcn_global_load_lds(
      (const __attribute__((address_space(1))) void*)g,
      (__attribute__((address_space(3))) void*)l, 16, 0, 0);
}

// ---------------------------------------------------------------- cast x -> bf16
__global__ __launch_bounds__(256) void cast_x_kernel(const float* __restrict__ x,
                                                     bf16_t* __restrict__ xb) {
  size_t i = (size_t)blockIdx.x * 256 + threadIdx.x;
  float4 v = ((const float4*)x)[i];
  bf16x4 o = {(bf16_t)v.x, (bf16_t)v.y, (bf16_t)v.z, (bf16_t)v.w};
  ((bf16x4*)xb)[i] = o;
}

// ------------------------------------------- transpose weights fp32[R][C] -> bf16[C][R]
__global__ __launch_bounds__(256) void transpose_w_kernel(
    const float* __restrict__ Wq, const float* __restrict__ Wk,
    const float* __restrict__ Wv, const float* __restrict__ Wo,
    bf16_t* __restrict__ Wt, bf16_t* __restrict__ WoT) {
  __shared__ bf16_t T[64 * 68];
  const int z = blockIdx.z;
  const float* src = (z == 0) ? Wq : (z == 1) ? Wk : (z == 2) ? Wv : Wo;
  bf16_t* dst = (z < 3) ? (Wt + (size_t)z * 1024 * 1024) : WoT;
  const int tr = blockIdx.y * 64;  // src row base (D)
  const int tc = blockIdx.x * 64;  // src col base (N)
  const int tid = threadIdx.x;
#pragma unroll
  for (int it = 0; it < 4; ++it) {
    int t = tid + it * 256;
    int row = t >> 4, c4 = t & 15;
    float4 v = *(const float4*)&src[(size_t)(tr + row) * 1024 + tc + c4 * 4];
    bf16x4 o = {(bf16_t)v.x, (bf16_t)v.y, (bf16_t)v.z, (bf16_t)v.w};
    *(bf16x4*)&T[row * 68 + c4 * 4] = o;
  }
  __syncthreads();
#pragma unroll
  for (int it = 0; it < 2; ++it) {
    int t = tid + it * 256;
    int n = t >> 3, d8 = t & 7;
    bf16x8 o;
#pragma unroll
    for (int j = 0; j < 8; ++j) o[j] = T[(d8 * 8 + j) * 68 + n];
    *(bf16x8*)&dst[(size_t)(tc + n) * 1024 + tr + d8 * 8] = o;
  }
}

// ================= 256x256 4-barrier GEMM core (bf16, K=1024, BK=64) =================
// 512 threads = 8 waves (2 M-waves x 4 N-waves). Per-wave C: 128x64 = 8x4 16x16 frags.
// LDS: 2 buffers x 4 regions {A0,A1,B0,B1} x (128 rows x 64 cols) bf16 = 128 KiB.
// Each wave reads ONLY its A-half (wm) and its B-region (wn>>1): 24 ds_read_b128/tile,
// ALL issued at tile start in region order [bfr01(4), af0-3(8), bfr23(4), af4-7(8)],
// so delivery overlaps MFMA. Counted per-wave drains gate the quadrants:
//   lgkm(12) -> Q00 (mf0-3 x nf0-1) ; lgkm(8) -> Q01 (mf0-3 x nf2-3) ; BAR
//     (at this BAR every wave has drained pos<=16 = ALL of its B reads)
//   stage B0(t+2) ; lgkm(0) -> Q11 (mf4-7 x nf2-3) ; BAR
//     (all waves fully drained: A regions safe)
//   stage A0(t+2) ; Q10 (mf4-7 x nf0-1, regs only) ; vmcnt ; BAR
// Stages B1/A1(t+1)->nbuf issue in the pre-section (nbuf fully read in tile t-1).
// vmcnt ledger: 8 gl_lds ops/tile; entering tile: 4 in flight {B0,A0}(t+1); pre adds
// 4 -> 8; P3/P4 add 4 -> 12; vmcnt(4) drains the 8 oldest = ALL of tile t+1. Tail
// (t>=14): no prefetch -> vmcnt(0). 4 barriers/tile.
// NOTE: __launch_bounds__(512, 2) is REQUIRED: 24 live bf16x8 fragments + acc
// need ~250 unified regs/wave; without the min-waves hint the compiler caps at
// 128 arch VGPRs and spills to scratch in the inner loop (r4: +22MB WRITE_SIZE,
// MfmaUtil 42->27). LDS already limits to 1 block/CU = 2 waves/SIMD, so the
// hint costs nothing.

__device__ __forceinline__ void stage_half(const bf16_t* __restrict__ g,
                                           bf16_t* l, const int tid) {
#pragma unroll
  for (int j = 0; j < 2; ++j) {
    int idx = j * 512 + tid;
    int row = idx >> 3;
    int c = (idx & 7) ^ (row & 7);  // inverse swizzle on the global side
    gl_lds16(g + (size_t)row * 1024 + c * 8, l + idx * 8);
  }
}

__device__ __forceinline__ void tile_step(const int t, bf16_t* const buf,
                                          bf16_t* const nbuf,
                                          const bf16_t* __restrict__ Ab,
                                          const bf16_t* __restrict__ Bb,
                                          f32x4 (&acc)[8][4], const int tid) {
  const int l15 = tid & 15, quad = (tid >> 4) & 3;
  const int wv = tid >> 6, wm = wv >> 2, wn = wv & 3;
  const int sx = l15 & 7;
  const int brow0 = (wn & 1) * 64;
  const bf16_t* const Ar = buf + wm * 8192;
  const bf16_t* const Br = buf + (2 + (wn >> 1)) * 8192;

  bf16x8 af[8][2], bfr[4][2];

  // ---- pre: all 24 ds_reads, region-ordered, then next-tile B1/A1 stages
#pragma unroll
  for (int nf = 0; nf < 2; ++nf)
#pragma unroll
    for (int ks = 0; ks < 2; ++ks)
      bfr[nf][ks] = *(const bf16x8*)&Br[(brow0 + nf * 16 + l15) * 64 +
                                        (((ks * 4 + quad) ^ sx) << 3)];
  FENCE;
#pragma unroll
  for (int mf = 0; mf < 4; ++mf)
#pragma unroll
    for (int ks = 0; ks < 2; ++ks)
      af[mf][ks] = *(const bf16x8*)&Ar[(mf * 16 + l15) * 64 +
                                       (((ks * 4 + quad) ^ sx) << 3)];
  FENCE;
#pragma unroll
  for (int nf = 2; nf < 4; ++nf)
#pragma unroll
    for (int ks = 0; ks < 2; ++ks)
      bfr[nf][ks] = *(const bf16x8*)&Br[(brow0 + nf * 16 + l15) * 64 +
                                        (((ks * 4 + quad) ^ sx) << 3)];
  FENCE;
#pragma unroll
  for (int mf = 4; mf < 8; ++mf)
#pragma unroll
    for (int ks = 0; ks < 2; ++ks)
      af[mf][ks] = *(const bf16x8*)&Ar[(mf * 16 + l15) * 64 +
                                       (((ks * 4 + quad) ^ sx) << 3)];
  FENCE;
  if (t + 1 < 16) {
    stage_half(Bb + 128 * 1024 + (t + 1) * 64, nbuf + 3 * 8192, tid);
    stage_half(Ab + 128 * 1024 + (t + 1) * 64, nbuf + 1 * 8192, tid);
  }
  BAR();

  // ---- M1: Q00 after first 12 reads (bfr01 + af0-3)
  WAITLGKM(12);
  __builtin_amdgcn_s_setprio(1);
#pragma unroll
  for (int ks = 0; ks < 2; ++ks)
#pragma unroll
    for (int mf = 0; mf < 4; ++mf)
#pragma unroll
      for (int nf = 0; nf < 2; ++nf)
        acc[mf][nf] = MFMA16(af[mf][ks], bfr[nf][ks], acc[mf][nf]);
  __builtin_amdgcn_s_setprio(0);

  // ---- M2: Q01 after bfr23 (pos<=16)
  WAITLGKM(8);
  __builtin_amdgcn_s_setprio(1);
#pragma unroll
  for (int ks = 0; ks < 2; ++ks)
#pragma unroll
    for (int mf = 0; mf < 4; ++mf)
#pragma unroll
      for (int nf = 2; nf < 4; ++nf)
        acc[mf][nf] = MFMA16(af[mf][ks], bfr[nf][ks], acc[mf][nf]);
  __builtin_amdgcn_s_setprio(0);
  BAR();  // all waves drained pos<=16: every wave's B reads delivered

  // ---- P3: stage B0(t+2) into current buf; Q11 after full drain
  if (t + 2 < 16) stage_half(Bb + (t + 2) * 64, buf + 2 * 8192, tid);
  WAITLGKM(0);
  __builtin_amdgcn_s_setprio(1);
#pragma unroll
  for (int ks = 0; ks < 2; ++ks)
#pragma unroll
    for (int mf = 4; mf < 8; ++mf)
#pragma unroll
      for (int nf = 2; nf < 4; ++nf)
        acc[mf][nf] = MFMA16(af[mf][ks], bfr[nf][ks], acc[mf][nf]);
  __builtin_amdgcn_s_setprio(0);
  BAR();  // all waves at lgkm(0): A regions safe to overwrite

  // ---- P4: stage A0(t+2); Q10 (registers only); counted vmcnt; bar
  if (t + 2 < 16) stage_half(Ab + (t + 2) * 64, buf + 0 * 8192, tid);
  __builtin_amdgcn_s_setprio(1);
#pragma unroll
  for (int ks = 0; ks < 2; ++ks)
#pragma unroll
    for (int mf = 4; mf < 8; ++mf)
#pragma unroll
      for (int nf = 0; nf < 2; ++nf)
        acc[mf][nf] = MFMA16(af[mf][ks], bfr[nf][ks], acc[mf][nf]);
  __builtin_amdgcn_s_setprio(0);
  if (t < 14)
    asm volatile("s_waitcnt vmcnt(4)" ::: "memory");  // drains ALL of tile t+1
  else
    asm volatile("s_waitcnt vmcnt(0)" ::: "memory");  // tail: no prefetch issued
  BAR();
}

__device__ __forceinline__ void gemm256_main(const bf16_t* __restrict__ Ab,
                                             const bf16_t* __restrict__ Bb,
                                             bf16_t* lds, f32x4 (&acc)[8][4],
                                             const int tid) {
  // prologue: tile0 {B0,A0,B1,A1}, tile1 {B0,A0}
  stage_half(Bb, lds + 2 * 8192, tid);
  stage_half(Ab, lds + 0 * 8192, tid);
  stage_half(Bb + 128 * 1024, lds + 3 * 8192, tid);
  stage_half(Ab + 128 * 1024, lds + 1 * 8192, tid);
  stage_half(Bb + 64, lds + 6 * 8192, tid);
  stage_half(Ab + 64, lds + 4 * 8192, tid);
  asm volatile("s_waitcnt vmcnt(4)" ::: "memory");  // tile0 landed
  BAR();

  for (int t = 0; t < 16; t += 2) {
    tile_step(t, lds, lds + 32768, Ab, Bb, acc, tid);
    tile_step(t + 1, lds + 32768, lds, Ab, Bb, acc, tid);
  }
}

// ----------------------------------------------------------------- QKV GEMM 256x256
// A: xb [16384][1024], Bt: Wt [3072][1024] (B^T), C: QKV [16384][3072] bf16.
// Q part (cols<1024) scaled by 1/sqrt(64)=0.125 after bias.
// Epilogue: per-wave LDS transpose (f32, 4 passes of 32 rows, pitch 68) so each
// 16-lane group emits one aligned 128B bf16x4 line -> no write amplification.
__global__ __launch_bounds__(512, 2) void gemm_qkv_kernel(
    const bf16_t* __restrict__ A, const bf16_t* __restrict__ Bt,
    const float* __restrict__ bq, const float* __restrict__ bk,
    const float* __restrict__ bv, bf16_t* __restrict__ C) {
  __shared__ bf16_t lds[2 * 4 * 8192];  // 128 KiB
  const int tid = threadIdx.x;
  // bijective XCD swizzle: 768 blocks, 96 contiguous tiles per XCD
  const int lin = blockIdx.x;
  const int swz = (lin & 7) * 96 + (lin >> 3);
  const int bm = swz / 12, bn = swz - bm * 12;

  f32x4 acc[8][4];
#pragma unroll
  for (int i = 0; i < 8; ++i)
#pragma unroll
    for (int j = 0; j < 4; ++j)
#pragma unroll
      for (int e = 0; e < 4; ++e) acc[i][j][e] = 0.f;

  gemm256_main(A + (size_t)(bm * 256) * 1024, Bt + (size_t)(bn * 256) * 1024,
               lds, acc, tid);

  const int l15 = tid & 15, quad = (tid >> 4) & 3;
  const int wv = tid >> 6, wm = wv >> 2, wn = wv & 3;
  const int col0 = bn * 256 + wn * 64;
  const int rbase = bm * 256 + wm * 128;
  float* R = (float*)(lds + wv * 8192);  // private 16 KiB per wave (post-main reuse)

  float wbias[4], wscale[4];
#pragma unroll
  for (int nf = 0; nf < 4; ++nf) {
    int col = col0 + nf * 16 + l15;
    if (col < 1024) {
      wbias[nf] = bq[col];
      wscale[nf] = 0.125f;
    } else if (col < 2048) {
      wbias[nf] = bk[col - 1024];
      wscale[nf] = 1.f;
    } else {
      wbias[nf] = bv[col - 2048];
      wscale[nf] = 1.f;
    }
  }
#pragma unroll
  for (int p = 0; p < 4; ++p) {
#pragma unroll
    for (int mfi = 0; mfi < 2; ++mfi) {
#pragma unroll
      for (int nf = 0; nf < 4; ++nf)
#pragma unroll
        for (int r = 0; r < 4; ++r)
          R[(mfi * 16 + quad * 4 + r) * 68 + nf * 16 + l15] =
              (acc[p * 2 + mfi][nf][r] + wbias[nf]) * wscale[nf];
    }
    WAITLGKM(0);  // wave-local: writes drained before reads
#pragma unroll
    for (int i = 0; i < 8; ++i) {
      const int lr = i * 4 + quad;
      f32x4 vv = *(const f32x4*)&R[lr * 68 + l15 * 4];
      bf16x4 o = {(bf16_t)vv[0], (bf16_t)vv[1], (bf16_t)vv[2], (bf16_t)vv[3]};
      int row = rbase + p * 32 + lr;
      *(bf16x4*)&C[(size_t)row * 3072 + col0 + l15 * 4] = o;
    }
    WAITLGKM(0);  // reads drained before next pass overwrites
  }
}

// ----------------------------------------------------------------- attention v3
// Per block: one (b,w,h) head, 128 query rows (2 q-tiles of 16 per wave).
__global__ __launch_bounds__(256) void attn_kernel(
    const bf16_t* __restrict__ QKV, bf16_t* __restrict__ Ctx) {
  __shared__ bf16_t Ks[64 * 64];      // [key][dim], XOR-swizzled granules
  __shared__ bf16_t Vs[64 * 64];      // [dim][key], XOR-swizzled granules
  __shared__ bf16_t Pb[4][16 * 64];   // per-wave P scratch [q][key], swizzled

  const int tid = threadIdx.x;
  const int wv = tid >> 6, quad = (tid >> 4) & 3, l15 = tid & 15;
  const int hid = blockIdx.x, qb = blockIdx.y;  // qb in 0..3
  const int b = hid >> 7, w = (hid >> 4) & 7, h = hid & 15;
  const int rowW = b * 4096 + w * 512;
  const int qbase = qb * 128 + wv * 32;

  bf16x8 qf[2][2];
#pragma unroll
  for (int qt = 0; qt < 2; ++qt) {
    int rowQ = rowW + qbase + qt * 16 + l15;
#pragma unroll
    for (int kh = 0; kh < 2; ++kh)
      qf[qt][kh] = *(const bf16x8*)&QKV[(size_t)rowQ * 3072 + h * 64 + kh * 32 + quad * 8];
  }

  const bf16_t* Kb = QKV + (size_t)rowW * 3072 + 1024 + h * 64;
  const bf16_t* Vg = QKV + (size_t)rowW * 3072 + 2048 + h * 64;

  float lp[2] = {0.f, 0.f};
  f32x4 Oa[2][4];
  f32x4 zero = {0.f, 0.f, 0.f, 0.f};
#pragma unroll
  for (int qt = 0; qt < 2; ++qt)
#pragma unroll
    for (int dt = 0; dt < 4; ++dt) Oa[qt][dt] = zero;

  const int vrow = tid >> 2;  // 0..63: source V row (s)
  const int vseg = tid & 3;   // 0..3: 16 d-values each

  for (int kt = 0; kt < 8; ++kt) {
#pragma unroll
    for (int i = 0; i < 2; ++i) {
      int t = tid + i * 256;
      int row = t >> 3;
      int g = (t & 7) ^ (row & 7);
      gl_lds16(Kb + (size_t)(kt * 64 + row) * 3072 + g * 8, &Ks[t * 8]);
    }
    {
      const bf16_t* src = Vg + (size_t)(kt * 64 + vrow) * 3072 + vseg * 16;
      bf16x8 v0 = *(const bf16x8*)&src[0];
      bf16x8 v1 = *(const bf16x8*)&src[8];
      int sg = vrow >> 3, sr = vrow & 7;
#pragma unroll
      for (int j = 0; j < 8; ++j) {
        int d0 = vseg * 16 + j;
        Vs[d0 * 64 + ((sg ^ (d0 & 7)) << 3) + sr] = v0[j];
        int d1 = vseg * 16 + 8 + j;
        Vs[d1 * 64 + ((sg ^ (d1 & 7)) << 3) + sr] = v1[j];
      }
    }
    __syncthreads();

    bf16x8 kf[4][2], vf[2][4];
#pragma unroll
    for (int jt = 0; jt < 4; ++jt) {
      int key = jt * 16 + l15;
#pragma unroll
      for (int kh = 0; kh < 2; ++kh)
        kf[jt][kh] = *(const bf16x8*)&Ks[key * 64 + (((kh * 4 + quad) ^ (key & 7)) << 3)];
    }
#pragma unroll
    for (int kh = 0; kh < 2; ++kh)
#pragma unroll
      for (int dt = 0; dt < 4; ++dt) {
        int d = dt * 16 + l15;
        vf[kh][dt] = *(const bf16x8*)&Vs[d * 64 + (((kh * 4 + quad) ^ (d & 7)) << 3)];
      }

#pragma unroll
    for (int qt = 0; qt < 2; ++qt) {
      f32x4 st[4];
#pragma unroll
      for (int jt = 0; jt < 4; ++jt) {
        f32x4 a = zero;
#pragma unroll
        for (int kh = 0; kh < 2; ++kh) a = MFMA16(kf[jt][kh], qf[qt][kh], a);
        st[jt] = a;
      }
      float ls = 0.f;
#pragma unroll
      for (int jt = 0; jt < 4; ++jt)
#pragma unroll
        for (int r = 0; r < 4; ++r) {
          float p = __expf(st[jt][r]);
          st[jt][r] = p;
          ls += p;
        }
      lp[qt] += ls;
#pragma unroll
      for (int jt = 0; jt < 4; ++jt) {
        bf16x4 pk = {(bf16_t)st[jt][0], (bf16_t)st[jt][1],
                     (bf16_t)st[jt][2], (bf16_t)st[jt][3]};
        int gs = (jt * 2 + (quad >> 1)) ^ (l15 & 7);
        *(bf16x4*)&Pb[wv][l15 * 64 + gs * 8 + (quad & 1) * 4] = pk;
      }
#pragma unroll
      for (int kh = 0; kh < 2; ++kh) {
        bf16x8 pf = *(const bf16x8*)&Pb[wv][l15 * 64 + (((kh * 4 + quad) ^ (l15 & 7)) << 3)];
#pragma unroll
        for (int dt = 0; dt < 4; ++dt) Oa[qt][dt] = MFMA16(pf, vf[kh][dt], Oa[qt][dt]);
      }
    }
    __syncthreads();
  }

#pragma unroll
  for (int qt = 0; qt < 2; ++qt) {
    float t = lp[qt];
    t += __shfl_xor(t, 16, 64);
    t += __shfl_xor(t, 32, 64);
    float inv_l = 1.0f / t;
    float inv[4];
#pragma unroll
    for (int r = 0; r < 4; ++r) inv[r] = __shfl(inv_l, quad * 4 + r, 64);
#pragma unroll
    for (int dt = 0; dt < 4; ++dt)
#pragma unroll
      for (int r = 0; r < 4; ++r) {
        int orow = rowW + qbase + qt * 16 + quad * 4 + r;
        Ctx[(size_t)orow * 1024 + h * 64 + dt * 16 + l15] = (bf16_t)(Oa[qt][dt][r] * inv[r]);
      }
  }
}

// ----------------------------------------------------------------- output proj 256x256
// Yb = bf16(ctx @ Wo + bo + x). Same coalesced LDS-transpose epilogue; bias and
// residual folded in the read phase (all-f32, single bf16 round as before).
__global__ __launch_bounds__(512, 2) void gemm_proj_kernel(
    const bf16_t* __restrict__ A, const bf16_t* __restrict__ Bt,
    const float* __restrict__ bo, const float* __restrict__ x,
    bf16_t* __restrict__ Yb) {
  __shared__ bf16_t lds[2 * 4 * 8192];  // 128 KiB
  const int tid = threadIdx.x;
  const int lin = blockIdx.x;  // 256 blocks
  const int swz = (lin & 7) * 32 + (lin >> 3);
  const int bm = swz >> 2, bn = swz & 3;

  f32x4 acc[8][4];
#pragma unroll
  for (int i = 0; i < 8; ++i)
#pragma unroll
    for (int j = 0; j < 4; ++j)
#pragma unroll
      for (int e = 0; e < 4; ++e) acc[i][j][e] = 0.f;

  gemm256_main(A + (size_t)(bm * 256) * 1024, Bt + (size_t)(bn * 256) * 1024,
               lds, acc, tid);

  const int l15 = tid & 15, quad = (tid >> 4) & 3;
  const int wv = tid >> 6, wm = wv >> 2, wn = wv & 3;
  const int col0 = bn * 256 + wn * 64;
  const int rbase = bm * 256 + wm * 128;
  float* R = (float*)(lds + wv * 8192);
  const int colg = col0 + l15 * 4;
  const float4 bo4 = *(const float4*)&bo[colg];

#pragma unroll
  for (int p = 0; p < 4; ++p) {
#pragma unroll
    for (int mfi = 0; mfi < 2; ++mfi) {
#pragma unroll
      for (int nf = 0; nf < 4; ++nf)
#pragma unroll
        for (int r = 0; r < 4; ++r)
          R[(mfi * 16 + quad * 4 + r) * 68 + nf * 16 + l15] = acc[p * 2 + mfi][nf][r];
    }
    WAITLGKM(0);
#pragma unroll
    for (int i = 0; i < 8; ++i) {
      const int lr = i * 4 + quad;
      int row = rbase + p * 32 + lr;
      f32x4 vv = *(const f32x4*)&R[lr * 68 + l15 * 4];
      float4 xv = *(const float4*)&x[(size_t)row * 1024 + colg];
      bf16x4 o = {(bf16_t)(vv[0] + bo4.x + xv.x), (bf16_t)(vv[1] + bo4.y + xv.y),
                  (bf16_t)(vv[2] + bo4.z + xv.z), (bf16_t)(vv[3] + bo4.w + xv.w)};
      *(bf16x4*)&Yb[(size_t)row * 1024 + colg] = o;
    }
    WAITLGKM(0);
  }
}

// ----------------------------------------------------------------- layernorm
__global__ __launch_bounds__(256) void ln_kernel(const bf16_t* __restrict__ Yb,
                                                 float* __restrict__ Y,
                                                 const float* __restrict__ gamma,
                                                 const float* __restrict__ beta) {
  const int row = blockIdx.x, tid = threadIdx.x;
  bf16x4 yb = ((const bf16x4*)(Yb + (size_t)row * 1024))[tid];
  float y0 = (float)yb[0], y1 = (float)yb[1], y2 = (float)yb[2], y3 = (float)yb[3];
  float s = y0 + y1 + y2 + y3;
  float s2 = y0 * y0 + y1 * y1 + y2 * y2 + y3 * y3;
#pragma unroll
  for (int off = 1; off < 64; off <<= 1) {
    s += __shfl_xor(s, off, 64);
    s2 += __shfl_xor(s2, off, 64);
  }
  __shared__ float red[8];
  int wv = tid >> 6;
  if ((tid & 63) == 0) {
    red[wv] = s;
    red[4 + wv] = s2;
  }
  __syncthreads();
  s = red[0] + red[1] + red[2] + red[3];
  s2 = red[4] + red[5] + red[6] + red[7];
  float mean = s * (1.0f / 1024.0f);
  float var = s2 * (1.0f / 1024.0f) - mean * mean;
  float rs = rsqrtf(var + 1e-3f);
  float4 g = ((const float4*)gamma)[tid];
  float4 bb = ((const float4*)beta)[tid];
  float4 o;
  o.x = (y0 - mean) * rs * g.x + bb.x;
  o.y = (y1 - mean) * rs * g.y + bb.y;
  o.z = (y2 - mean) * rs * g.z + bb.z;
  o.w = (y3 - mean) * rs * g.w + bb.w;
  ((float4*)(Y + (size_t)row * 1024))[tid] = o;
}

extern "C" void kernel_launch(void* const* d_in, const int* in_sizes, int n_in,
                              void* d_out, int out_size, void* d_ws, size_t ws_size,
                              hipStream_t stream) {
  const float* x = (const float*)d_in[0];
  const float* Wq = (const float*)d_in[1];
  const float* bq = (const float*)d_in[2];
  const float* Wk = (const float*)d_in[3];
  const float* bk = (const float*)d_in[4];
  const float* Wv = (const float*)d_in[5];
  const float* bv = (const float*)d_in[6];
  const float* Wo = (const float*)d_in[7];
  const float* bo = (const float*)d_in[8];
  const float* gamma = (const float*)d_in[9];
  const float* beta = (const float*)d_in[10];
  float* Y = (float*)d_out;

  char* ws = (char*)d_ws;
  bf16_t* xb = (bf16_t*)(ws);                   // 16384*1024 bf16 = 32MB
  bf16_t* Wt = (bf16_t*)(ws + 33554432);        // 3072*1024 bf16 = 6MB
  bf16_t* WoT = (bf16_t*)(ws + 39845888);       // 1024*1024 bf16 = 2MB
  bf16_t* QKVb = (bf16_t*)(ws + 41943040);      // 16384*3072 bf16 = 96MB
  bf16_t* Ctx = (bf16_t*)(ws + 142606336);      // 16384*1024 bf16 = 32MB
  bf16_t* Yb = (bf16_t*)(ws + 176160768);       // 16384*1024 bf16 = 32MB

  cast_x_kernel<<<16384, 256, 0, stream>>>(x, xb);
  transpose_w_kernel<<<dim3(16, 16, 4), 256, 0, stream>>>(Wq, Wk, Wv, Wo, Wt, WoT);
  gemm_qkv_kernel<<<768, 512, 0, stream>>>(xb, Wt, bq, bk, bv, QKVb);
  attn_kernel<<<dim3(512, 4), 256, 0, stream>>>(QKVb, Ctx);
  gemm_proj_kernel<<<256, 512, 0, stream>>>(Ctx, WoT, bo, x, Yb);
  ln_kernel<<<16384, 256, 0, stream>>>(Yb, Y, gamma, beta);
}

// Round 7
// 365.861 us; speedup vs baseline: 1.1443x; 1.1443x over previous
//
#include <hip/hip_runtime.h>

typedef __bf16 bf16_t;
typedef __bf16 bf16x4 __attribute__((ext_vector_type(4)));
typedef __bf16 bf16x8 __attribute__((ext_vector_type(8)));
typedef float f32x4 __attribute__((ext_vector_type(4)));

#define MFMA16(a, b, c) __builtin_amdgcn_mfma_f32_16x16x32_bf16((a), (b), (c), 0, 0, 0)

#define FENCE asm volatile("" ::: "memory")
#define BAR()                        \
  do {                               \
    FENCE;                           \
    __builtin_amdgcn_s_barrier();    \
    FENCE;                           \
  } while (0)
#define WAITLGKM(n) asm volatile("s_waitcnt lgkmcnt(" #n ")" ::: "memory")

// async global->LDS, 16B per lane. LDS dest must be wave-uniform base + lane*16.
__device__ __forceinline__ void gl_lds16(const bf16_t* g, bf16_t* l) {
  __builtin_amdgcn_global_load_lds(
      (const __attribute__((address_space(1))) void*)g,
      (__attribute__((address_space(3))) void*)l, 16, 0, 0);
}

// ---------------------------------------------------------------- cast x -> bf16
__global__ __launch_bounds__(256) void cast_x_kernel(const float* __restrict__ x,
                                                     bf16_t* __restrict__ xb) {
  size_t i = (size_t)blockIdx.x * 256 + threadIdx.x;
  float4 v = ((const float4*)x)[i];
  bf16x4 o = {(bf16_t)v.x, (bf16_t)v.y, (bf16_t)v.z, (bf16_t)v.w};
  ((bf16x4*)xb)[i] = o;
}

// ------------------------------------------- transpose weights fp32[R][C] -> bf16[C][R]
__global__ __launch_bounds__(256) void transpose_w_kernel(
    const float* __restrict__ Wq, const float* __restrict__ Wk,
    const float* __restrict__ Wv, const float* __restrict__ Wo,
    bf16_t* __restrict__ Wt, bf16_t* __restrict__ WoT) {
  __shared__ bf16_t T[64 * 68];
  const int z = blockIdx.z;
  const float* src = (z == 0) ? Wq : (z == 1) ? Wk : (z == 2) ? Wv : Wo;
  bf16_t* dst = (z < 3) ? (Wt + (size_t)z * 1024 * 1024) : WoT;
  const int tr = blockIdx.y * 64;  // src row base (D)
  const int tc = blockIdx.x * 64;  // src col base (N)
  const int tid = threadIdx.x;
#pragma unroll
  for (int it = 0; it < 4; ++it) {
    int t = tid + it * 256;
    int row = t >> 4, c4 = t & 15;
    float4 v = *(const float4*)&src[(size_t)(tr + row) * 1024 + tc + c4 * 4];
    bf16x4 o = {(bf16_t)v.x, (bf16_t)v.y, (bf16_t)v.z, (bf16_t)v.w};
    *(bf16x4*)&T[row * 68 + c4 * 4] = o;
  }
  __syncthreads();
#pragma unroll
  for (int it = 0; it < 2; ++it) {
    int t = tid + it * 256;
    int n = t >> 3, d8 = t & 7;
    bf16x8 o;
#pragma unroll
    for (int j = 0; j < 8; ++j) o[j] = T[(d8 * 8 + j) * 68 + n];
    *(bf16x8*)&dst[(size_t)(tc + n) * 1024 + tr + d8 * 8] = o;
  }
}

// ================= 256x256 3-barrier GEMM core (bf16, K=1024, BK=64) =================
// 512 threads = 8 waves (2M x 4N). Per-wave C: 128x64 = 8x4 16x16 frags.
// LDS: 2 buffers x 4 regions {A0,A1,B0,B1} x (128 rows x 64 cols) bf16 = 128 KiB.
// Fragment live set capped at 16 bf16x8 (64 VGPR): acc (128 f32) occupies the AGPR
// half of the 256-reg unified budget, so arch VGPRs are hard-capped at 128 (r4/r5
// lesson: af[8] spilled regardless of __launch_bounds__).
// Per-tile schedule (buf = t&1):
//   pre: 16 reads [bfr01(4) | af01(4) | af23(4) | bfr23(4)] ; stage B1,A1(t+1)->nbuf
//   lgkm(8) -> 8 MFMA (mf01 x nf01)       [bfr23/af23 drain under MFMA]
//   lgkm(4) -> 8 MFMA (mf23 x nf01)
//   lgkm(0) -> 16 MFMA (mf0-3 x nf23) ; BAR#1  [all waves: B reads + af0-3 drained]
//   stage B0(t+2)->buf ; read af45(4)|af67(4)
//   lgkm(4) -> 8 MFMA (mf45 x nf23)       [af67 drains under MFMA]
//   lgkm(0) -> 8 MFMA (mf67 x nf23) ; BAR#2  [all waves: all A reads drained]
//   stage A0(t+2)->buf ; 16 MFMA (mf4-7 x nf01, regs only) ; vmcnt ; BAR#3
// WAR: B0 overwrite after BAR#1 (B reads drained); A0 overwrite after BAR#2;
// pre stages->nbuf safe (tile t-1 drained all reads before its BAR#2/#3).
// vmcnt ledger (as r3, proven): 8 gl_lds/tile; entering t: 4 in flight {B0,A0}(t+1);
// at P4 wait 12 in flight; vmcnt(4) drains 8 oldest = ALL of buf(t+1).
// Tail t>=14: no prefetch -> vmcnt(0).

__device__ __forceinline__ void stage_half(const bf16_t* __restrict__ g,
                                           bf16_t* l, const int tid) {
#pragma unroll
  for (int j = 0; j < 2; ++j) {
    int idx = j * 512 + tid;
    int row = idx >> 3;
    int c = (idx & 7) ^ (row & 7);  // inverse swizzle on the global side
    gl_lds16(g + (size_t)row * 1024 + c * 8, l + idx * 8);
  }
}

__device__ __forceinline__ void tile_step(const int t, bf16_t* const buf,
                                          bf16_t* const nbuf,
                                          const bf16_t* __restrict__ Ab,
                                          const bf16_t* __restrict__ Bb,
                                          f32x4 (&acc)[8][4], const int tid) {
  const int l15 = tid & 15, quad = (tid >> 4) & 3;
  const int wv = tid >> 6, wm = wv >> 2, wn = wv & 3;
  const int sx = l15 & 7;
  const int brow0 = (wn & 1) * 64;
  const bf16_t* const Ar = buf + wm * 8192;
  const bf16_t* const Br = buf + (2 + (wn >> 1)) * 8192;

  bf16x8 af[4][2], bfr[4][2];

  // ---- pre: 16 reads, order pinned, then next-tile B1/A1 stages
#pragma unroll
  for (int nf = 0; nf < 2; ++nf)
#pragma unroll
    for (int ks = 0; ks < 2; ++ks)
      bfr[nf][ks] = *(const bf16x8*)&Br[(brow0 + nf * 16 + l15) * 64 +
                                        (((ks * 4 + quad) ^ sx) << 3)];
  FENCE;
#pragma unroll
  for (int mf = 0; mf < 2; ++mf)
#pragma unroll
    for (int ks = 0; ks < 2; ++ks)
      af[mf][ks] = *(const bf16x8*)&Ar[(mf * 16 + l15) * 64 +
                                       (((ks * 4 + quad) ^ sx) << 3)];
  FENCE;
#pragma unroll
  for (int mf = 2; mf < 4; ++mf)
#pragma unroll
    for (int ks = 0; ks < 2; ++ks)
      af[mf][ks] = *(const bf16x8*)&Ar[(mf * 16 + l15) * 64 +
                                       (((ks * 4 + quad) ^ sx) << 3)];
  FENCE;
#pragma unroll
  for (int nf = 2; nf < 4; ++nf)
#pragma unroll
    for (int ks = 0; ks < 2; ++ks)
      bfr[nf][ks] = *(const bf16x8*)&Br[(brow0 + nf * 16 + l15) * 64 +
                                        (((ks * 4 + quad) ^ sx) << 3)];
  FENCE;
  if (t + 1 < 16) {
    stage_half(Bb + 128 * 1024 + (t + 1) * 64, nbuf + 3 * 8192, tid);
    stage_half(Ab + 128 * 1024 + (t + 1) * 64, nbuf + 1 * 8192, tid);
  }

  // ---- M1a: first 8 reads (bfr01 + af01)
  WAITLGKM(8);
  __builtin_amdgcn_s_setprio(1);
#pragma unroll
  for (int ks = 0; ks < 2; ++ks)
#pragma unroll
    for (int mf = 0; mf < 2; ++mf)
#pragma unroll
      for (int nf = 0; nf < 2; ++nf)
        acc[mf][nf] = MFMA16(af[mf][ks], bfr[nf][ks], acc[mf][nf]);
  __builtin_amdgcn_s_setprio(0);

  // ---- M1b: + af23
  WAITLGKM(4);
  __builtin_amdgcn_s_setprio(1);
#pragma unroll
  for (int ks = 0; ks < 2; ++ks)
#pragma unroll
    for (int mf = 2; mf < 4; ++mf)
#pragma unroll
      for (int nf = 0; nf < 2; ++nf)
        acc[mf][nf] = MFMA16(af[mf][ks], bfr[nf][ks], acc[mf][nf]);
  __builtin_amdgcn_s_setprio(0);

  // ---- M2: + bfr23
  WAITLGKM(0);
  __builtin_amdgcn_s_setprio(1);
#pragma unroll
  for (int ks = 0; ks < 2; ++ks)
#pragma unroll
    for (int mf = 0; mf < 4; ++mf)
#pragma unroll
      for (int nf = 2; nf < 4; ++nf)
        acc[mf][nf] = MFMA16(af[mf][ks], bfr[nf][ks], acc[mf][nf]);
  __builtin_amdgcn_s_setprio(0);
  BAR();  // #1: all waves drained B reads + af0-3

  // ---- P3: stage B0(t+2); read A rows 64-127 (reuse af regs)
  if (t + 2 < 16) stage_half(Bb + (t + 2) * 64, buf + 2 * 8192, tid);
#pragma unroll
  for (int mf = 0; mf < 2; ++mf)
#pragma unroll
    for (int ks = 0; ks < 2; ++ks)
      af[mf][ks] = *(const bf16x8*)&Ar[((mf + 4) * 16 + l15) * 64 +
                                       (((ks * 4 + quad) ^ sx) << 3)];
  FENCE;
#pragma unroll
  for (int mf = 2; mf < 4; ++mf)
#pragma unroll
    for (int ks = 0; ks < 2; ++ks)
      af[mf][ks] = *(const bf16x8*)&Ar[((mf + 4) * 16 + l15) * 64 +
                                       (((ks * 4 + quad) ^ sx) << 3)];
  FENCE;
  WAITLGKM(4);  // af45 landed
  __builtin_amdgcn_s_setprio(1);
#pragma unroll
  for (int ks = 0; ks < 2; ++ks)
#pragma unroll
    for (int mf = 0; mf < 2; ++mf)
#pragma unroll
      for (int nf = 2; nf < 4; ++nf)
        acc[mf + 4][nf] = MFMA16(af[mf][ks], bfr[nf][ks], acc[mf + 4][nf]);
  __builtin_amdgcn_s_setprio(0);
  WAITLGKM(0);  // af67 landed
  __builtin_amdgcn_s_setprio(1);
#pragma unroll
  for (int ks = 0; ks < 2; ++ks)
#pragma unroll
    for (int mf = 2; mf < 4; ++mf)
#pragma unroll
      for (int nf = 2; nf < 4; ++nf)
        acc[mf + 4][nf] = MFMA16(af[mf][ks], bfr[nf][ks], acc[mf + 4][nf]);
  __builtin_amdgcn_s_setprio(0);
  BAR();  // #2: all waves drained all A reads

  // ---- P4: stage A0(t+2); Q10 regs-only; counted vmcnt; bar
  if (t + 2 < 16) stage_half(Ab + (t + 2) * 64, buf + 0 * 8192, tid);
  __builtin_amdgcn_s_setprio(1);
#pragma unroll
  for (int ks = 0; ks < 2; ++ks)
#pragma unroll
    for (int mf = 0; mf < 4; ++mf)
#pragma unroll
      for (int nf = 0; nf < 2; ++nf)
        acc[mf + 4][nf] = MFMA16(af[mf][ks], bfr[nf][ks], acc[mf + 4][nf]);
  __builtin_amdgcn_s_setprio(0);
  if (t < 14)
    asm volatile("s_waitcnt vmcnt(4)" ::: "memory");  // drains ALL of tile t+1
  else
    asm volatile("s_waitcnt vmcnt(0)" ::: "memory");  // tail: no prefetch issued
  BAR();  // #3
}

__device__ __forceinline__ void gemm256_main(const bf16_t* __restrict__ Ab,
                                             const bf16_t* __restrict__ Bb,
                                             bf16_t* lds, f32x4 (&acc)[8][4],
                                             const int tid) {
  // prologue: tile0 {B0,A0,B1,A1}, tile1 {B0,A0}
  stage_half(Bb, lds + 2 * 8192, tid);
  stage_half(Ab, lds + 0 * 8192, tid);
  stage_half(Bb + 128 * 1024, lds + 3 * 8192, tid);
  stage_half(Ab + 128 * 1024, lds + 1 * 8192, tid);
  stage_half(Bb + 64, lds + 6 * 8192, tid);
  stage_half(Ab + 64, lds + 4 * 8192, tid);
  asm volatile("s_waitcnt vmcnt(4)" ::: "memory");  // tile0 landed
  BAR();

  for (int t = 0; t < 16; t += 2) {
    tile_step(t, lds, lds + 32768, Ab, Bb, acc, tid);
    tile_step(t + 1, lds + 32768, lds, Ab, Bb, acc, tid);
  }
}

// ----------------------------------------------------------------- QKV GEMM 256x256
// A: xb [16384][1024], Bt: Wt [3072][1024] (B^T), C: QKV [16384][3072] bf16.
// Q part (cols<1024) scaled by 1/sqrt(64)=0.125 after bias.
// Epilogue: per-wave LDS transpose (f32, 4 passes of 32 rows, pitch 68) so each
// 16-lane group emits one aligned 128B bf16x4 line -> no write amplification.
__global__ __launch_bounds__(512, 2) void gemm_qkv_kernel(
    const bf16_t* __restrict__ A, const bf16_t* __restrict__ Bt,
    const float* __restrict__ bq, const float* __restrict__ bk,
    const float* __restrict__ bv, bf16_t* __restrict__ C) {
  __shared__ bf16_t lds[2 * 4 * 8192];  // 128 KiB
  const int tid = threadIdx.x;
  // bijective XCD swizzle: 768 blocks, 96 contiguous tiles per XCD
  const int lin = blockIdx.x;
  const int swz = (lin & 7) * 96 + (lin >> 3);
  const int bm = swz / 12, bn = swz - bm * 12;

  f32x4 acc[8][4];
#pragma unroll
  for (int i = 0; i < 8; ++i)
#pragma unroll
    for (int j = 0; j < 4; ++j)
#pragma unroll
      for (int e = 0; e < 4; ++e) acc[i][j][e] = 0.f;

  gemm256_main(A + (size_t)(bm * 256) * 1024, Bt + (size_t)(bn * 256) * 1024,
               lds, acc, tid);

  const int l15 = tid & 15, quad = (tid >> 4) & 3;
  const int wv = tid >> 6, wm = wv >> 2, wn = wv & 3;
  const int col0 = bn * 256 + wn * 64;
  const int rbase = bm * 256 + wm * 128;
  float* R = (float*)(lds + wv * 8192);  // private 16 KiB per wave (post-main reuse)

  float wbias[4], wscale[4];
#pragma unroll
  for (int nf = 0; nf < 4; ++nf) {
    int col = col0 + nf * 16 + l15;
    if (col < 1024) {
      wbias[nf] = bq[col];
      wscale[nf] = 0.125f;
    } else if (col < 2048) {
      wbias[nf] = bk[col - 1024];
      wscale[nf] = 1.f;
    } else {
      wbias[nf] = bv[col - 2048];
      wscale[nf] = 1.f;
    }
  }
#pragma unroll
  for (int p = 0; p < 4; ++p) {
#pragma unroll
    for (int mfi = 0; mfi < 2; ++mfi) {
#pragma unroll
      for (int nf = 0; nf < 4; ++nf)
#pragma unroll
        for (int r = 0; r < 4; ++r)
          R[(mfi * 16 + quad * 4 + r) * 68 + nf * 16 + l15] =
              (acc[p * 2 + mfi][nf][r] + wbias[nf]) * wscale[nf];
    }
    WAITLGKM(0);  // wave-local: writes drained before reads
#pragma unroll
    for (int i = 0; i < 8; ++i) {
      const int lr = i * 4 + quad;
      f32x4 vv = *(const f32x4*)&R[lr * 68 + l15 * 4];
      bf16x4 o = {(bf16_t)vv[0], (bf16_t)vv[1], (bf16_t)vv[2], (bf16_t)vv[3]};
      int row = rbase + p * 32 + lr;
      *(bf16x4*)&C[(size_t)row * 3072 + col0 + l15 * 4] = o;
    }
    WAITLGKM(0);  // reads drained before next pass overwrites
  }
}

// ----------------------------------------------------------------- attention v4
// Per block: one (b,w,h) head, 128 query rows (2 q-tiles of 16 per wave).
// T14 pipeline: V(kt+1) reg-loads + K(kt+1) gl_lds issued at top of iter kt,
// drained by counted vmcnt(4); Ks/Vs double-buffered. Raw s_barrier (NOT
// __syncthreads -- that drains vmcnt(0) and would kill the pipeline).
// vmcnt ledger: 4 VMEM ops/iter (2 V loads + 2 K gl_lds); entering iter kt:
// 4 in flight {V(kt),K(kt)}; after issue: 8; vmcnt(4) drains the 4 oldest.
// Prologue's 8 (4 qf + 2 V0 + 2 K0) are the oldest at kt=0 -> drained there.
// Tail kt=7: nothing issued -> vmcnt(0).
__global__ __launch_bounds__(256) void attn_kernel(
    const bf16_t* __restrict__ QKV, bf16_t* __restrict__ Ctx) {
  __shared__ bf16_t Ks[2][64 * 64];   // [key][dim], XOR-swizzled granules
  __shared__ bf16_t Vs[2][64 * 64];   // [dim][key], XOR-swizzled granules
  __shared__ bf16_t Pb[4][16 * 64];   // per-wave P scratch [q][key], swizzled

  const int tid = threadIdx.x;
  const int wv = tid >> 6, quad = (tid >> 4) & 3, l15 = tid & 15;
  const int hid = blockIdx.x, qb = blockIdx.y;  // qb in 0..3
  const int b = hid >> 7, w = (hid >> 4) & 7, h = hid & 15;
  const int rowW = b * 4096 + w * 512;
  const int qbase = qb * 128 + wv * 32;

  bf16x8 qf[2][2];
#pragma unroll
  for (int qt = 0; qt < 2; ++qt) {
    int rowQ = rowW + qbase + qt * 16 + l15;
#pragma unroll
    for (int kh = 0; kh < 2; ++kh)
      qf[qt][kh] = *(const bf16x8*)&QKV[(size_t)rowQ * 3072 + h * 64 + kh * 32 + quad * 8];
  }

  const bf16_t* Kb = QKV + (size_t)rowW * 3072 + 1024 + h * 64;
  const bf16_t* Vg = QKV + (size_t)rowW * 3072 + 2048 + h * 64;

  float lp[2] = {0.f, 0.f};
  f32x4 Oa[2][4];
  f32x4 zero = {0.f, 0.f, 0.f, 0.f};
#pragma unroll
  for (int qt = 0; qt < 2; ++qt)
#pragma unroll
    for (int dt = 0; dt < 4; ++dt) Oa[qt][dt] = zero;

  const int vrow = tid >> 2;  // 0..63: source V row (s)
  const int vseg = tid & 3;   // 0..3: 16 d-values each
  const int sg = vrow >> 3, sr = vrow & 7;

  // prologue: V(0) -> regs, K(0) -> Ks[0]
  bf16x8 vr0, vr1;
  {
    const bf16_t* src = Vg + (size_t)vrow * 3072 + vseg * 16;
    vr0 = *(const bf16x8*)&src[0];
    vr1 = *(const bf16x8*)&src[8];
  }
  FENCE;
#pragma unroll
  for (int i = 0; i < 2; ++i) {
    int t = tid + i * 256;
    int row = t >> 3;
    int g = (t & 7) ^ (row & 7);
    gl_lds16(Kb + (size_t)row * 3072 + g * 8, &Ks[0][t * 8]);
  }
  FENCE;

#pragma unroll 2
  for (int kt = 0; kt < 8; ++kt) {
    const int cb = kt & 1;
    bf16x8 vn0 = vr0, vn1 = vr1;
    if (kt < 7) {
      const bf16_t* src = Vg + (size_t)((kt + 1) * 64 + vrow) * 3072 + vseg * 16;
      vn0 = *(const bf16x8*)&src[0];
      vn1 = *(const bf16x8*)&src[8];
      FENCE;
#pragma unroll
      for (int i = 0; i < 2; ++i) {
        int t = tid + i * 256;
        int row = t >> 3;
        int g = (t & 7) ^ (row & 7);
        gl_lds16(Kb + (size_t)((kt + 1) * 64 + row) * 3072 + g * 8, &Ks[cb ^ 1][t * 8]);
      }
      asm volatile("s_waitcnt vmcnt(4)" ::: "memory");  // V(kt) regs + K(kt) landed
    } else {
      asm volatile("s_waitcnt vmcnt(0)" ::: "memory");  // tail drain
    }
    // write V(kt) regs -> Vs[cb] (transposed + swizzled)
#pragma unroll
    for (int j = 0; j < 8; ++j) {
      int d0 = vseg * 16 + j;
      Vs[cb][d0 * 64 + ((sg ^ (d0 & 7)) << 3) + sr] = vr0[j];
      int d1 = vseg * 16 + 8 + j;
      Vs[cb][d1 * 64 + ((sg ^ (d1 & 7)) << 3) + sr] = vr1[j];
    }
    WAITLGKM(0);  // ds_writes drained
    BAR();        // K/V tile visible to all waves

    bf16x8 kf[4][2], vf[2][4];
#pragma unroll
    for (int jt = 0; jt < 4; ++jt) {
      int key = jt * 16 + l15;
#pragma unroll
      for (int kh = 0; kh < 2; ++kh)
        kf[jt][kh] = *(const bf16x8*)&Ks[cb][key * 64 + (((kh * 4 + quad) ^ (key & 7)) << 3)];
    }
#pragma unroll
    for (int kh = 0; kh < 2; ++kh)
#pragma unroll
      for (int dt = 0; dt < 4; ++dt) {
        int d = dt * 16 + l15;
        vf[kh][dt] = *(const bf16x8*)&Vs[cb][d * 64 + (((kh * 4 + quad) ^ (d & 7)) << 3)];
      }

#pragma unroll
    for (int qt = 0; qt < 2; ++qt) {
      f32x4 st[4];
#pragma unroll
      for (int jt = 0; jt < 4; ++jt) {
        f32x4 a = zero;
#pragma unroll
        for (int kh = 0; kh < 2; ++kh) a = MFMA16(kf[jt][kh], qf[qt][kh], a);
        st[jt] = a;
      }
      float ls = 0.f;
#pragma unroll
      for (int jt = 0; jt < 4; ++jt)
#pragma unroll
        for (int r = 0; r < 4; ++r) {
          float p = __expf(st[jt][r]);
          st[jt][r] = p;
          ls += p;
        }
      lp[qt] += ls;
#pragma unroll
      for (int jt = 0; jt < 4; ++jt) {
        bf16x4 pk = {(bf16_t)st[jt][0], (bf16_t)st[jt][1],
                     (bf16_t)st[jt][2], (bf16_t)st[jt][3]};
        int gs = (jt * 2 + (quad >> 1)) ^ (l15 & 7);
        *(bf16x4*)&Pb[wv][l15 * 64 + gs * 8 + (quad & 1) * 4] = pk;
      }
#pragma unroll
      for (int kh = 0; kh < 2; ++kh) {
        bf16x8 pf = *(const bf16x8*)&Pb[wv][l15 * 64 + (((kh * 4 + quad) ^ (l15 & 7)) << 3)];
#pragma unroll
        for (int dt = 0; dt < 4; ++dt) Oa[qt][dt] = MFMA16(pf, vf[kh][dt], Oa[qt][dt]);
      }
    }
    WAITLGKM(0);  // all LDS reads of this tile drained (WAR anchor)
    BAR();
    vr0 = vn0;
    vr1 = vn1;
  }

  // epilogue: reduce l over the 4 quads sharing q=l15, then redistribute inv
#pragma unroll
  for (int qt = 0; qt < 2; ++qt) {
    float t = lp[qt];
    t += __shfl_xor(t, 16, 64);
    t += __shfl_xor(t, 32, 64);
    float inv_l = 1.0f / t;
    float inv[4];
#pragma unroll
    for (int r = 0; r < 4; ++r) inv[r] = __shfl(inv_l, quad * 4 + r, 64);
#pragma unroll
    for (int dt = 0; dt < 4; ++dt)
#pragma unroll
      for (int r = 0; r < 4; ++r) {
        int orow = rowW + qbase + qt * 16 + quad * 4 + r;
        Ctx[(size_t)orow * 1024 + h * 64 + dt * 16 + l15] = (bf16_t)(Oa[qt][dt][r] * inv[r]);
      }
  }
}

// ----------------------------------------------------------------- output proj 256x256
// Yb = bf16(ctx @ Wo + bo + x). Same coalesced LDS-transpose epilogue; bias and
// residual folded in the read phase (all-f32, single bf16 round as before).
__global__ __launch_bounds__(512, 2) void gemm_proj_kernel(
    const bf16_t* __restrict__ A, const bf16_t* __restrict__ Bt,
    const float* __restrict__ bo, const float* __restrict__ x,
    bf16_t* __restrict__ Yb) {
  __shared__ bf16_t lds[2 * 4 * 8192];  // 128 KiB
  const int tid = threadIdx.x;
  const int lin = blockIdx.x;  // 256 blocks
  const int swz = (lin & 7) * 32 + (lin >> 3);
  const int bm = swz >> 2, bn = swz & 3;

  f32x4 acc[8][4];
#pragma unroll
  for (int i = 0; i < 8; ++i)
#pragma unroll
    for (int j = 0; j < 4; ++j)
#pragma unroll
      for (int e = 0; e < 4; ++e) acc[i][j][e] = 0.f;

  gemm256_main(A + (size_t)(bm * 256) * 1024, Bt + (size_t)(bn * 256) * 1024,
               lds, acc, tid);

  const int l15 = tid & 15, quad = (tid >> 4) & 3;
  const int wv = tid >> 6, wm = wv >> 2, wn = wv & 3;
  const int col0 = bn * 256 + wn * 64;
  const int rbase = bm * 256 + wm * 128;
  float* R = (float*)(lds + wv * 8192);
  const int colg = col0 + l15 * 4;
  const float4 bo4 = *(const float4*)&bo[colg];

#pragma unroll
  for (int p = 0; p < 4; ++p) {
#pragma unroll
    for (int mfi = 0; mfi < 2; ++mfi) {
#pragma unroll
      for (int nf = 0; nf < 4; ++nf)
#pragma unroll
        for (int r = 0; r < 4; ++r)
          R[(mfi * 16 + quad * 4 + r) * 68 + nf * 16 + l15] = acc[p * 2 + mfi][nf][r];
    }
    WAITLGKM(0);
#pragma unroll
    for (int i = 0; i < 8; ++i) {
      const int lr = i * 4 + quad;
      int row = rbase + p * 32 + lr;
      f32x4 vv = *(const f32x4*)&R[lr * 68 + l15 * 4];
      float4 xv = *(const float4*)&x[(size_t)row * 1024 + colg];
      bf16x4 o = {(bf16_t)(vv[0] + bo4.x + xv.x), (bf16_t)(vv[1] + bo4.y + xv.y),
                  (bf16_t)(vv[2] + bo4.z + xv.z), (bf16_t)(vv[3] + bo4.w + xv.w)};
      *(bf16x4*)&Yb[(size_t)row * 1024 + colg] = o;
    }
    WAITLGKM(0);
  }
}

// ----------------------------------------------------------------- layernorm
__global__ __launch_bounds__(256) void ln_kernel(const bf16_t* __restrict__ Yb,
                                                 float* __restrict__ Y,
                                                 const float* __restrict__ gamma,
                                                 const float* __restrict__ beta) {
  const int row = blockIdx.x, tid = threadIdx.x;
  bf16x4 yb = ((const bf16x4*)(Yb + (size_t)row * 1024))[tid];
  float y0 = (float)yb[0], y1 = (float)yb[1], y2 = (float)yb[2], y3 = (float)yb[3];
  float s = y0 + y1 + y2 + y3;
  float s2 = y0 * y0 + y1 * y1 + y2 * y2 + y3 * y3;
#pragma unroll
  for (int off = 1; off < 64; off <<= 1) {
    s += __shfl_xor(s, off, 64);
    s2 += __shfl_xor(s2, off, 64);
  }
  __shared__ float red[8];
  int wv = tid >> 6;
  if ((tid & 63) == 0) {
    red[wv] = s;
    red[4 + wv] = s2;
  }
  __syncthreads();
  s = red[0] + red[1] + red[2] + red[3];
  s2 = red[4] + red[5] + red[6] + red[7];
  float mean = s * (1.0f / 1024.0f);
  float var = s2 * (1.0f / 1024.0f) - mean * mean;
  float rs = rsqrtf(var + 1e-3f);
  float4 g = ((const float4*)gamma)[tid];
  float4 bb = ((const float4*)beta)[tid];
  float4 o;
  o.x = (y0 - mean) * rs * g.x + bb.x;
  o.y = (y1 - mean) * rs * g.y + bb.y;
  o.z = (y2 - mean) * rs * g.z + bb.z;
  o.w = (y3 - mean) * rs * g.w + bb.w;
  ((float4*)(Y + (size_t)row * 1024))[tid] = o;
}

extern "C" void kernel_launch(void* const* d_in, const int* in_sizes, int n_in,
                              void* d_out, int out_size, void* d_ws, size_t ws_size,
                              hipStream_t stream) {
  const float* x = (const float*)d_in[0];
  const float* Wq = (const float*)d_in[1];
  const float* bq = (const float*)d_in[2];
  const float* Wk = (const float*)d_in[3];
  const float* bk = (const float*)d_in[4];
  const float* Wv = (const float*)d_in[5];
  const float* bv = (const float*)d_in[6];
  const float* Wo = (const float*)d_in[7];
  const float* bo = (const float*)d_in[8];
  const float* gamma = (const float*)d_in[9];
  const float* beta = (const float*)d_in[10];
  float* Y = (float*)d_out;

  char* ws = (char*)d_ws;
  bf16_t* xb = (bf16_t*)(ws);                   // 16384*1024 bf16 = 32MB
  bf16_t* Wt = (bf16_t*)(ws + 33554432);        // 3072*1024 bf16 = 6MB
  bf16_t* WoT = (bf16_t*)(ws + 39845888);       // 1024*1024 bf16 = 2MB
  bf16_t* QKVb = (bf16_t*)(ws + 41943040);      // 16384*3072 bf16 = 96MB
  bf16_t* Ctx = (bf16_t*)(ws + 142606336);      // 16384*1024 bf16 = 32MB
  bf16_t* Yb = (bf16_t*)(ws + 176160768);       // 16384*1024 bf16 = 32MB

  cast_x_kernel<<<16384, 256, 0, stream>>>(x, xb);
  transpose_w_kernel<<<dim3(16, 16, 4), 256, 0, stream>>>(Wq, Wk, Wv, Wo, Wt, WoT);
  gemm_qkv_kernel<<<768, 512, 0, stream>>>(xb, Wt, bq, bk, bv, QKVb);
  attn_kernel<<<dim3(512, 4), 256, 0, stream>>>(QKVb, Ctx);
  gemm_proj_kernel<<<256, 512, 0, stream>>>(Ctx, WoT, bo, x, Yb);
  ln_kernel<<<16384, 256, 0, stream>>>(Yb, Y, gamma, beta);
}